// Round 13
// baseline (353.030 us; speedup 1.0000x reference)
//
#include <hip/hip_runtime.h>
#include <float.h>

#define N_TOK   32768
#define DIM     64
#define K_CODES 8192
#define HWSZ    1024
#define CHW     65536
#define NELEM   2097152

typedef short  bf16x8 __attribute__((ext_vector_type(8)));
typedef float  f32x16 __attribute__((ext_vector_type(16)));

static __device__ __forceinline__ unsigned short f2bf(float x) {
    unsigned u = __float_as_uint(x);
    unsigned r = u + 0x7FFFu + ((u >> 16) & 1u);
    return (unsigned short)(r >> 16);
}
static __device__ __forceinline__ float bf2f(unsigned short h) {
    return __uint_as_float(((unsigned)h) << 16);
}

// ------- prep_e: emb -> frag-ordered bf16 hi/lo blob + ||e||^2 + ws init -----
// Also inits emao_out = 0.99*ema_w and zeroes tile_ctr (per-tile election).
__global__ __launch_bounds__(256) void prep_e(const float* __restrict__ emb,
                                              const float* __restrict__ ema_w,
                                              const float* __restrict__ csize,
                                              unsigned short* __restrict__ blob,
                                              float* __restrict__ eng,
                                              unsigned long long* __restrict__ packed,
                                              int* __restrict__ cnt_i,
                                              float* __restrict__ sums,
                                              float* __restrict__ emao_out,
                                              int* __restrict__ tile_ctr) {
    __shared__ float part[512];
    __shared__ float csp[4];
    const int gid = blockIdx.x * 256 + threadIdx.x;   // 0..32767
    packed[gid] = ~0ull;                              // init for atomicMin
    if (gid < K_CODES) cnt_i[gid] = 0;
    if (gid < 512) tile_ctr[gid] = 0;
    if (gid == 1) sums[1] = 0.f;                      // loss accumulator

    // emao init: 16 strided elements per thread, coalesced
    #pragma unroll
    for (int j = 0; j < 16; ++j) {
        int i = gid + j * 32768;
        emao_out[i] = 0.99f * ema_w[i];
    }

    // block 0: S_cs = sum(csize) -> sums[0]
    if (blockIdx.x == 0) {
        float s = 0.f;
        #pragma unroll
        for (int j = 0; j < 32; ++j) s += csize[threadIdx.x * 32 + j];
        #pragma unroll
        for (int m = 32; m >= 1; m >>= 1) s += __shfl_xor(s, m, 64);
        if ((threadIdx.x & 63) == 0) csp[threadIdx.x >> 6] = s;
        __syncthreads();
        if (threadIdx.x == 0) sums[0] = csp[0] + csp[1] + csp[2] + csp[3];
    }

    int tile = blockIdx.x;
    #pragma unroll
    for (int u0 = 0; u0 < 2; ++u0) {
        int u = threadIdx.x + u0 * 256;
        int s = u >> 7, h = (u >> 6) & 1, n = u & 63;
        const float* src = emb + (tile * 64 + n) * 64 + s * 16 + h * 8;
        float4 v0 = *(const float4*)src;
        float4 v1 = *(const float4*)(src + 4);
        float x[8] = {v0.x, v0.y, v0.z, v0.w, v1.x, v1.y, v1.z, v1.w};
        unsigned short hi[8], lo[8];
        float ss = 0.f;
        #pragma unroll
        for (int j = 0; j < 8; ++j) {
            hi[j] = f2bf(x[j]);
            lo[j] = f2bf(x[j] - bf2f(hi[j]));
            ss += x[j] * x[j];
        }
        part[u] = ss;
        unsigned short* dhi = blob + (size_t)tile * 8192 + ((s * 2 + 0) * 2 + h) * 512 + n * 8;
        unsigned short* dlo = blob + (size_t)tile * 8192 + ((s * 2 + 1) * 2 + h) * 512 + n * 8;
        uint4 ph, pl;
        ph.x = (unsigned)hi[0] | ((unsigned)hi[1] << 16);
        ph.y = (unsigned)hi[2] | ((unsigned)hi[3] << 16);
        ph.z = (unsigned)hi[4] | ((unsigned)hi[5] << 16);
        ph.w = (unsigned)hi[6] | ((unsigned)hi[7] << 16);
        pl.x = (unsigned)lo[0] | ((unsigned)lo[1] << 16);
        pl.y = (unsigned)lo[2] | ((unsigned)lo[3] << 16);
        pl.z = (unsigned)lo[4] | ((unsigned)lo[5] << 16);
        pl.w = (unsigned)lo[6] | ((unsigned)lo[7] << 16);
        *(uint4*)dhi = ph;
        *(uint4*)dlo = pl;
    }
    __syncthreads();
    if (threadIdx.x < 64) {
        float s = 0.f;
        #pragma unroll
        for (int j = 0; j < 8; ++j) s += part[threadIdx.x + j * 64];
        eng[tile * 64 + threadIdx.x] = s;
    }
}

// ------- vq_fused: R10-exact argmin main loop + per-tile elected zq phase ----
// Main loop/seed/MFMA/merge identical to R10 (K-split 2, grid 1024) ->
// argmin picks unchanged. After atomicMin + fence, the 2 blocks of each
// token-tile race tile_ctr[tb]; the LAST does the zq work for its 64 tokens
// (zq_loss v3's exact expressions), reusing the block's LDS as a union.
// Election work is 1/512 scale and overlaps with other tiles' vq blocks.
__global__ __launch_bounds__(256, 3) void vq_fused(const float* __restrict__ z,
                                                   const unsigned short* __restrict__ blob,
                                                   const float* __restrict__ eng,
                                                   unsigned long long* __restrict__ packed,
                                                   const float* __restrict__ emb,
                                                   float* __restrict__ zq_out,
                                                   float* __restrict__ idx_out,
                                                   int* __restrict__ cnt_i,
                                                   float* __restrict__ loss_sum,
                                                   float* __restrict__ emao_out,
                                                   int* __restrict__ tile_ctr) {
    // LDS union: main phase {zh 9216 | zl 9216 | red 2048} = 20480
    //            zq phase   {e_lds 17408 | z_lds 17408 | idx_s 256} = 35072
    __shared__ __align__(16) char lds_raw[35072];
    __shared__ int is_last;
    unsigned short* zh = (unsigned short*)lds_raw;                    // [64*72]
    unsigned short* zl = (unsigned short*)(lds_raw + 9216);           // [64*72]
    unsigned long long* red = (unsigned long long*)(lds_raw + 18432); // [64*4]

    const int tid  = threadIdx.x;
    const int lane = tid & 63;
    const int wid  = tid >> 6;           // 0..3
    const int l31  = lane & 31, h = lane >> 5;

    const int tb = blockIdx.x & 511;     // token-tile id 0..511
    const int ks = blockIdx.x >> 9;      // K split 0/1
    const int n0 = tb * 64;
    const int zbase = (n0 >> 10) * CHW + (n0 & 1023);

    // ---- stage -2*z as bf16 hi/lo (64 tokens x 64 dims) ----
    {
        int f4 = tid & 15;               // 16 float4 = 64 tokens per channel
        int c0 = tid >> 4;               // 0..15
        #pragma unroll
        for (int r = 0; r < 4; ++r) {
            int c = c0 * 4 + r;
            float4 v = *(const float4*)(z + zbase + c * HWSZ + f4 * 4);
            float x[4] = {v.x, v.y, v.z, v.w};
            #pragma unroll
            for (int e = 0; e < 4; ++e) {
                int t = f4 * 4 + e;
                float xs = -2.0f * x[e];
                unsigned short hi = f2bf(xs);
                zh[t * 72 + c] = hi;
                zl[t * 72 + c] = f2bf(xs - bf2f(hi));
            }
        }
    }
    __syncthreads();

    // ---- resident token fragments (B operand), both 32-token tiles ----
    bf16x8 T0h[4], T0l[4], T1h[4], T1l[4];
    {
        int r0 = l31;        // tile 0 token
        int r1 = 32 + l31;   // tile 1 token
        #pragma unroll
        for (int s = 0; s < 4; ++s) {
            T0h[s] = *(const bf16x8*)(&zh[r0 * 72 + s * 16 + h * 8]);
            T0l[s] = *(const bf16x8*)(&zl[r0 * 72 + s * 16 + h * 8]);
            T1h[s] = *(const bf16x8*)(&zh[r1 * 72 + s * 16 + h * 8]);
            T1l[s] = *(const bf16x8*)(&zl[r1 * 72 + s * 16 + h * 8]);
        }
    }

    const int hk0 = ks * 128 + wid;
    const unsigned short* bp = blob + (size_t)(hk0 >> 1) * 8192 + ((hk0 & 1) * 32 + l31) * 8;
    const float* ep = eng + (hk0 >> 1) * 64 + (hk0 & 1) * 32 + 4 * h;
    int scode = __builtin_amdgcn_readfirstlane((hk0 >> 1) * 64 + (hk0 & 1) * 32);

    // prologue: first tile's E frags + eng
    bf16x8 Eh[4], El[4];
    #pragma unroll
    for (int s = 0; s < 4; ++s) {
        Eh[s] = *(const bf16x8*)(bp + (4 * s + h) * 512);
        El[s] = *(const bf16x8*)(bp + (4 * s + 2 + h) * 512);
    }
    float4 g0 = *(const float4*)(ep);
    float4 g1 = *(const float4*)(ep + 8);
    float4 g2 = *(const float4*)(ep + 16);
    float4 g3 = *(const float4*)(ep + 24);

    float minv0 = FLT_MAX, minv1 = FLT_MAX;
    int   mini0 = 0,       mini1 = 0;

    for (int i = 0; i < 32; ++i) {
        // seed acc with ||e||^2 (round-2 numerics: eng is the MFMA C operand)
        f32x16 ac0, ac1;
        ac0[0]  = g0.x; ac0[1]  = g0.y; ac0[2]  = g0.z; ac0[3]  = g0.w;
        ac0[4]  = g1.x; ac0[5]  = g1.y; ac0[6]  = g1.z; ac0[7]  = g1.w;
        ac0[8]  = g2.x; ac0[9]  = g2.y; ac0[10] = g2.z; ac0[11] = g2.w;
        ac0[12] = g3.x; ac0[13] = g3.y; ac0[14] = g3.z; ac0[15] = g3.w;
        ac1 = ac0;

        // prefetch next tile's eng (g regs dead after seed)
        ep += 128;
        g0 = *(const float4*)(ep);
        g1 = *(const float4*)(ep + 8);
        g2 = *(const float4*)(ep + 16);
        g3 = *(const float4*)(ep + 24);

        __builtin_amdgcn_s_setprio(1);
        #pragma unroll
        for (int s = 0; s < 4; ++s) {
            ac0 = __builtin_amdgcn_mfma_f32_32x32x16_bf16(El[s], T0h[s], ac0, 0, 0, 0);
            ac1 = __builtin_amdgcn_mfma_f32_32x32x16_bf16(El[s], T1h[s], ac1, 0, 0, 0);
            ac0 = __builtin_amdgcn_mfma_f32_32x32x16_bf16(Eh[s], T0l[s], ac0, 0, 0, 0);
            ac1 = __builtin_amdgcn_mfma_f32_32x32x16_bf16(Eh[s], T1l[s], ac1, 0, 0, 0);
            ac0 = __builtin_amdgcn_mfma_f32_32x32x16_bf16(Eh[s], T0h[s], ac0, 0, 0, 0);
            ac1 = __builtin_amdgcn_mfma_f32_32x32x16_bf16(Eh[s], T1h[s], ac1, 0, 0, 0);
        }
        __builtin_amdgcn_s_setprio(0);

        // prefetch next tile's E frags (E regs dead once MFMAs issued)
        bp += 2 * 8192;   // hk += 4  ->  2 kt tiles of 8192 shorts
        #pragma unroll
        for (int s = 0; s < 4; ++s) {
            Eh[s] = *(const bf16x8*)(bp + (4 * s + h) * 512);
            El[s] = *(const bf16x8*)(bp + (4 * s + 2 + h) * 512);
        }

        // epilogue: acc IS the distance; min-update (cmp + 2 sel)
        #pragma unroll
        for (int r = 0; r < 16; ++r) {
            int code = scode + ((r & 3) + 8 * (r >> 2));
            if (ac0[r] < minv0) { minv0 = ac0[r]; mini0 = code; }
            if (ac1[r] < minv1) { minv1 = ac1[r]; mini1 = code; }
        }
        scode += 128;
    }
    mini0 += 4 * h;   // lane-dependent part of code, applied once
    mini1 += 4 * h;

    // ---- merge h halves (same token, disjoint code rows), then waves ----
    unsigned u0 = __float_as_uint(minv0);
    u0 = (u0 & 0x80000000u) ? ~u0 : (u0 | 0x80000000u);
    unsigned long long k0 = ((unsigned long long)u0 << 32) | (unsigned)mini0;
    unsigned u1 = __float_as_uint(minv1);
    u1 = (u1 & 0x80000000u) ? ~u1 : (u1 | 0x80000000u);
    unsigned long long k1 = ((unsigned long long)u1 << 32) | (unsigned)mini1;
    unsigned long long o0 = __shfl_xor(k0, 32, 64);
    if (o0 < k0) k0 = o0;
    unsigned long long o1 = __shfl_xor(k1, 32, 64);
    if (o1 < k1) k1 = o1;
    if (h == 0) {
        red[l31 * 4 + wid]        = k0;
        red[(32 + l31) * 4 + wid] = k1;
    }
    __syncthreads();
    if (tid < 64) {
        unsigned long long a = red[tid * 4], b = red[tid * 4 + 1];
        unsigned long long c = red[tid * 4 + 2], d = red[tid * 4 + 3];
        unsigned long long m = (b < a) ? b : a;
        if (c < m) m = c;
        if (d < m) m = d;
        atomicMin(&packed[n0 + tid], m);
    }

    // ---- per-tile election: last of the 2 K-split blocks does zq ----
    __threadfence();
    __syncthreads();        // red consumed; LDS reusable after this point
    if (tid == 0) is_last = (atomicAdd(&tile_ctr[tb], 1) == 1);
    __syncthreads();
    if (!is_last) return;
    __threadfence();

    float* e_lds  = (float*)lds_raw;              // [64][68]
    float* z_ldsf = (float*)(lds_raw + 17408);    // [64][68]
    int*   idx_s  = (int*)(lds_raw + 34816);      // [64]

    if (tid < 64) {
        unsigned long long p = __hip_atomic_load(&packed[n0 + tid], __ATOMIC_RELAXED,
                                                 __HIP_MEMORY_SCOPE_AGENT);
        int ix = (int)(p & 0xFFFFFFFFull);
        idx_s[tid] = ix;
        idx_out[n0 + tid] = (float)ix;
        atomicAdd(&cnt_i[ix], 1);
    }
    __syncthreads();

    const int t = tid >> 2, q = tid & 3;
    const int ixt = idx_s[t];
    // gather emb row -> e_lds[t][q*16..]
    {
        const float* er = emb + ixt * 64 + q * 16;
        float4 e0 = *(const float4*)er,       e1 = *(const float4*)(er + 4);
        float4 e2 = *(const float4*)(er + 8), e3 = *(const float4*)(er + 12);
        *(float4*)&e_lds[t * 68 + q * 16]      = e0;
        *(float4*)&e_lds[t * 68 + q * 16 + 4]  = e1;
        *(float4*)&e_lds[t * 68 + q * 16 + 8]  = e2;
        *(float4*)&e_lds[t * 68 + q * 16 + 12] = e3;
    }
    // stage z channel-major (coalesced, L2-hot) -> z_ldsf[token][c]
    {
        const int f4 = tid & 15, c0 = tid >> 4;
        #pragma unroll
        for (int r = 0; r < 4; ++r) {
            int c = c0 * 4 + r;
            float4 v = *(const float4*)(z + zbase + c * HWSZ + f4 * 4);
            z_ldsf[(f4 * 4 + 0) * 68 + c] = v.x;
            z_ldsf[(f4 * 4 + 1) * 68 + c] = v.y;
            z_ldsf[(f4 * 4 + 2) * 68 + c] = v.z;
            z_ldsf[(f4 * 4 + 3) * 68 + c] = v.w;
        }
    }
    __syncthreads();

    // emao accumulation: wave wid handles tokens wid*16..+15, lane = dim
    #pragma unroll
    for (int u = 0; u < 16; ++u) {
        int tt = wid * 16 + u;
        atomicAdd(&emao_out[idx_s[tt] * 64 + lane], 0.01f * z_ldsf[tt * 68 + lane]);
    }
    // zq_out write: channel-major, fully coalesced; same per-element arithmetic
    {
        const int f4 = tid & 15, c0 = tid >> 4;
        #pragma unroll
        for (int r = 0; r < 4; ++r) {
            int c = c0 * 4 + r;
            float4 o;
            { float zv = z_ldsf[(f4*4+0)*68+c]; o.x = zv + (e_lds[(f4*4+0)*68+c] - zv); }
            { float zv = z_ldsf[(f4*4+1)*68+c]; o.y = zv + (e_lds[(f4*4+1)*68+c] - zv); }
            { float zv = z_ldsf[(f4*4+2)*68+c]; o.z = zv + (e_lds[(f4*4+2)*68+c] - zv); }
            { float zv = z_ldsf[(f4*4+3)*68+c]; o.w = zv + (e_lds[(f4*4+3)*68+c] - zv); }
            *(float4*)(zq_out + zbase + c * HWSZ + f4 * 4) = o;
        }
    }
    // loss: per-thread order identical to v3 (c = q*16+j ascending)
    float lsum = 0.f;
    #pragma unroll
    for (int j = 0; j < 16; ++j) {
        int c = q * 16 + j;
        float dd = e_lds[t * 68 + c] - z_ldsf[t * 68 + c];
        lsum += dd * dd;
    }
    #pragma unroll
    for (int m = 32; m >= 1; m >>= 1) lsum += __shfl_xor(lsum, m, 64);
    if ((tid & 63) == 0) atomicAdd(loss_sum, lsum);
}

// ------- norm_div: csn + embo + loss in one parallel pass --------------------
__global__ __launch_bounds__(256) void norm_div(const int* __restrict__ cnt_i,
                                                const float* __restrict__ csize,
                                                const float* __restrict__ sums,
                                                const float* __restrict__ emao_out,
                                                float* __restrict__ csn_out,
                                                float* __restrict__ loss_out,
                                                float* __restrict__ embo_out) {
    const int g = blockIdx.x * 256 + threadIdx.x;   // 0..524287
    const int c = g >> 6;
    const float denom = 0.99f * sums[0] + 0.01f * (float)N_TOK + (float)(K_CODES * 1e-5);
    const float cv  = 0.99f * csize[c] + 0.01f * (float)cnt_i[c];
    const float csn = (cv + 1e-5f) / denom;
    if ((g & 63) == 0) csn_out[c] = csn;
    embo_out[g] = emao_out[g] / csn;
    if (g == 0) *loss_out = 0.25f * sums[1] * (1.0f / (float)NELEM);
}

extern "C" void kernel_launch(void* const* d_in, const int* in_sizes, int n_in,
                              void* d_out, int out_size, void* d_ws, size_t ws_size,
                              hipStream_t stream) {
    (void)in_sizes; (void)n_in; (void)out_size; (void)ws_size;
    const float* z     = (const float*)d_in[0];
    const float* emb   = (const float*)d_in[1];
    const float* ema_w = (const float*)d_in[2];
    const float* csize = (const float*)d_in[3];

    float* out      = (float*)d_out;
    float* zq_out   = out;
    float* loss_out = out + 2097152;
    float* idx_out  = out + 2097153;
    float* csn_out  = out + 2129921;
    float* emao_out = out + 2138113;
    float* embo_out = out + 2662401;

    char* wsb = (char*)d_ws;
    unsigned short*     blob     = (unsigned short*)(wsb);              // 2,097,152 B
    float*              eng      = (float*)(wsb + 2097152);             // 32 KB
    unsigned long long* packed   = (unsigned long long*)(wsb + 2129920);// 256 KB
    int*                tile_ctr = (int*)(wsb + 2392064);               // 2 KB
    int*                cnt_i    = (int*)(wsb + 2523136);               // 32 KB
    float*              sums     = (float*)(wsb + 2555904);             // 8 B

    prep_e<<<128, 256, 0, stream>>>(emb, ema_w, csize, blob, eng, packed, cnt_i,
                                    sums, emao_out, tile_ctr);
    vq_fused<<<1024, 256, 0, stream>>>(z, blob, eng, packed, emb, zq_out, idx_out,
                                       cnt_i, sums + 1, emao_out, tile_ctr);
    norm_div<<<NELEM / 4 / 256, 256, 0, stream>>>(cnt_i, csize, sums, emao_out,
                                                  csn_out, loss_out, embo_out);
}

// Round 14
// 200.005 us; speedup vs baseline: 1.7651x; 1.7651x over previous
//
#include <hip/hip_runtime.h>
#include <float.h>

#define N_TOK   32768
#define DIM     64
#define K_CODES 8192
#define HWSZ    1024
#define CHW     65536
#define NELEM   2097152

typedef short  bf16x8 __attribute__((ext_vector_type(8)));
typedef float  f32x16 __attribute__((ext_vector_type(16)));

static __device__ __forceinline__ unsigned short f2bf(float x) {
    unsigned u = __float_as_uint(x);
    unsigned r = u + 0x7FFFu + ((u >> 16) & 1u);
    return (unsigned short)(r >> 16);
}
static __device__ __forceinline__ float bf2f(unsigned short h) {
    return __uint_as_float(((unsigned)h) << 16);
}

// ------- prep_e: emb -> frag-ordered bf16 hi/lo blob + ||e||^2 + ws init -----
// Also inits emao_out = 0.99*ema_w and block 0 computes S_cs = sum(csize).
__global__ __launch_bounds__(256) void prep_e(const float* __restrict__ emb,
                                              const float* __restrict__ ema_w,
                                              const float* __restrict__ csize,
                                              unsigned short* __restrict__ blob,
                                              float* __restrict__ eng,
                                              unsigned long long* __restrict__ packed,
                                              int* __restrict__ cnt_i,
                                              float* __restrict__ sums,
                                              float* __restrict__ emao_out) {
    __shared__ float part[512];
    __shared__ float csp[4];
    const int gid = blockIdx.x * 256 + threadIdx.x;   // 0..32767
    packed[gid] = ~0ull;                              // init for atomicMin
    if (gid < K_CODES) cnt_i[gid] = 0;
    if (gid == 1) sums[1] = 0.f;                      // loss accumulator

    // emao init: 16 strided elements per thread, coalesced
    #pragma unroll
    for (int j = 0; j < 16; ++j) {
        int i = gid + j * 32768;
        emao_out[i] = 0.99f * ema_w[i];
    }

    // block 0: S_cs = sum(csize) -> sums[0]
    if (blockIdx.x == 0) {
        float s = 0.f;
        #pragma unroll
        for (int j = 0; j < 32; ++j) s += csize[threadIdx.x * 32 + j];
        #pragma unroll
        for (int m = 32; m >= 1; m >>= 1) s += __shfl_xor(s, m, 64);
        if ((threadIdx.x & 63) == 0) csp[threadIdx.x >> 6] = s;
        __syncthreads();
        if (threadIdx.x == 0) sums[0] = csp[0] + csp[1] + csp[2] + csp[3];
    }

    int tile = blockIdx.x;
    #pragma unroll
    for (int u0 = 0; u0 < 2; ++u0) {
        int u = threadIdx.x + u0 * 256;
        int s = u >> 7, h = (u >> 6) & 1, n = u & 63;
        const float* src = emb + (tile * 64 + n) * 64 + s * 16 + h * 8;
        float4 v0 = *(const float4*)src;
        float4 v1 = *(const float4*)(src + 4);
        float x[8] = {v0.x, v0.y, v0.z, v0.w, v1.x, v1.y, v1.z, v1.w};
        unsigned short hi[8], lo[8];
        float ss = 0.f;
        #pragma unroll
        for (int j = 0; j < 8; ++j) {
            hi[j] = f2bf(x[j]);
            lo[j] = f2bf(x[j] - bf2f(hi[j]));
            ss += x[j] * x[j];
        }
        part[u] = ss;
        unsigned short* dhi = blob + (size_t)tile * 8192 + ((s * 2 + 0) * 2 + h) * 512 + n * 8;
        unsigned short* dlo = blob + (size_t)tile * 8192 + ((s * 2 + 1) * 2 + h) * 512 + n * 8;
        uint4 ph, pl;
        ph.x = (unsigned)hi[0] | ((unsigned)hi[1] << 16);
        ph.y = (unsigned)hi[2] | ((unsigned)hi[3] << 16);
        ph.z = (unsigned)hi[4] | ((unsigned)hi[5] << 16);
        ph.w = (unsigned)hi[6] | ((unsigned)hi[7] << 16);
        pl.x = (unsigned)lo[0] | ((unsigned)lo[1] << 16);
        pl.y = (unsigned)lo[2] | ((unsigned)lo[3] << 16);
        pl.z = (unsigned)lo[4] | ((unsigned)lo[5] << 16);
        pl.w = (unsigned)lo[6] | ((unsigned)lo[7] << 16);
        *(uint4*)dhi = ph;
        *(uint4*)dlo = pl;
    }
    __syncthreads();
    if (threadIdx.x < 64) {
        float s = 0.f;
        #pragma unroll
        for (int j = 0; j < 8; ++j) s += part[threadIdx.x + j * 64];
        eng[tile * 64 + threadIdx.x] = s;
    }
}

// ---------------- argmin: software-pipelined, eng-seeded acc (R10 exact) -----
__global__ __launch_bounds__(256, 3) void vq_argmin(const float* __restrict__ z,
                                                    const unsigned short* __restrict__ blob,
                                                    const float* __restrict__ eng,
                                                    unsigned long long* __restrict__ packed) {
    __shared__ __align__(16) unsigned short zh[64 * 72];
    __shared__ __align__(16) unsigned short zl[64 * 72];
    __shared__ unsigned long long red[64 * 4];

    const int tid  = threadIdx.x;
    const int lane = tid & 63;
    const int wid  = tid >> 6;           // 0..3
    const int l31  = lane & 31, h = lane >> 5;

    const int tb = blockIdx.x & 511;     // token-tile id 0..511
    const int ks = blockIdx.x >> 9;      // K split 0/1
    const int n0 = tb * 64;
    const int zbase = (n0 >> 10) * CHW + (n0 & 1023);

    // ---- stage -2*z as bf16 hi/lo (64 tokens x 64 dims) ----
    {
        int f4 = tid & 15;               // 16 float4 = 64 tokens per channel
        int c0 = tid >> 4;               // 0..15
        #pragma unroll
        for (int r = 0; r < 4; ++r) {
            int c = c0 * 4 + r;
            float4 v = *(const float4*)(z + zbase + c * HWSZ + f4 * 4);
            float x[4] = {v.x, v.y, v.z, v.w};
            #pragma unroll
            for (int e = 0; e < 4; ++e) {
                int t = f4 * 4 + e;
                float xs = -2.0f * x[e];
                unsigned short hi = f2bf(xs);
                zh[t * 72 + c] = hi;
                zl[t * 72 + c] = f2bf(xs - bf2f(hi));
            }
        }
    }
    __syncthreads();

    // ---- resident token fragments (B operand), both 32-token tiles ----
    bf16x8 T0h[4], T0l[4], T1h[4], T1l[4];
    {
        int r0 = l31;        // tile 0 token
        int r1 = 32 + l31;   // tile 1 token
        #pragma unroll
        for (int s = 0; s < 4; ++s) {
            T0h[s] = *(const bf16x8*)(&zh[r0 * 72 + s * 16 + h * 8]);
            T0l[s] = *(const bf16x8*)(&zl[r0 * 72 + s * 16 + h * 8]);
            T1h[s] = *(const bf16x8*)(&zh[r1 * 72 + s * 16 + h * 8]);
            T1l[s] = *(const bf16x8*)(&zl[r1 * 72 + s * 16 + h * 8]);
        }
    }

    const int hk0 = ks * 128 + wid;
    const unsigned short* bp = blob + (size_t)(hk0 >> 1) * 8192 + ((hk0 & 1) * 32 + l31) * 8;
    const float* ep = eng + (hk0 >> 1) * 64 + (hk0 & 1) * 32 + 4 * h;
    int scode = __builtin_amdgcn_readfirstlane((hk0 >> 1) * 64 + (hk0 & 1) * 32);

    // prologue: first tile's E frags + eng
    bf16x8 Eh[4], El[4];
    #pragma unroll
    for (int s = 0; s < 4; ++s) {
        Eh[s] = *(const bf16x8*)(bp + (4 * s + h) * 512);
        El[s] = *(const bf16x8*)(bp + (4 * s + 2 + h) * 512);
    }
    float4 g0 = *(const float4*)(ep);
    float4 g1 = *(const float4*)(ep + 8);
    float4 g2 = *(const float4*)(ep + 16);
    float4 g3 = *(const float4*)(ep + 24);

    float minv0 = FLT_MAX, minv1 = FLT_MAX;
    int   mini0 = 0,       mini1 = 0;

    for (int i = 0; i < 32; ++i) {
        // seed acc with ||e||^2 (round-2 numerics: eng is the MFMA C operand)
        f32x16 ac0, ac1;
        ac0[0]  = g0.x; ac0[1]  = g0.y; ac0[2]  = g0.z; ac0[3]  = g0.w;
        ac0[4]  = g1.x; ac0[5]  = g1.y; ac0[6]  = g1.z; ac0[7]  = g1.w;
        ac0[8]  = g2.x; ac0[9]  = g2.y; ac0[10] = g2.z; ac0[11] = g2.w;
        ac0[12] = g3.x; ac0[13] = g3.y; ac0[14] = g3.z; ac0[15] = g3.w;
        ac1 = ac0;

        // prefetch next tile's eng (g regs dead after seed)
        ep += 128;
        g0 = *(const float4*)(ep);
        g1 = *(const float4*)(ep + 8);
        g2 = *(const float4*)(ep + 16);
        g3 = *(const float4*)(ep + 24);

        __builtin_amdgcn_s_setprio(1);
        #pragma unroll
        for (int s = 0; s < 4; ++s) {
            ac0 = __builtin_amdgcn_mfma_f32_32x32x16_bf16(El[s], T0h[s], ac0, 0, 0, 0);
            ac1 = __builtin_amdgcn_mfma_f32_32x32x16_bf16(El[s], T1h[s], ac1, 0, 0, 0);
            ac0 = __builtin_amdgcn_mfma_f32_32x32x16_bf16(Eh[s], T0l[s], ac0, 0, 0, 0);
            ac1 = __builtin_amdgcn_mfma_f32_32x32x16_bf16(Eh[s], T1l[s], ac1, 0, 0, 0);
            ac0 = __builtin_amdgcn_mfma_f32_32x32x16_bf16(Eh[s], T0h[s], ac0, 0, 0, 0);
            ac1 = __builtin_amdgcn_mfma_f32_32x32x16_bf16(Eh[s], T1h[s], ac1, 0, 0, 0);
        }
        __builtin_amdgcn_s_setprio(0);

        // prefetch next tile's E frags (E regs dead once MFMAs issued)
        bp += 2 * 8192;   // hk += 4  ->  2 kt tiles of 8192 shorts
        #pragma unroll
        for (int s = 0; s < 4; ++s) {
            Eh[s] = *(const bf16x8*)(bp + (4 * s + h) * 512);
            El[s] = *(const bf16x8*)(bp + (4 * s + 2 + h) * 512);
        }

        // epilogue: acc IS the distance; min-update (cmp + 2 sel)
        #pragma unroll
        for (int r = 0; r < 16; ++r) {
            int code = scode + ((r & 3) + 8 * (r >> 2));
            if (ac0[r] < minv0) { minv0 = ac0[r]; mini0 = code; }
            if (ac1[r] < minv1) { minv1 = ac1[r]; mini1 = code; }
        }
        scode += 128;
    }
    mini0 += 4 * h;   // lane-dependent part of code, applied once
    mini1 += 4 * h;

    // ---- merge h halves (same token, disjoint code rows), then waves ----
    unsigned u0 = __float_as_uint(minv0);
    u0 = (u0 & 0x80000000u) ? ~u0 : (u0 | 0x80000000u);
    unsigned long long k0 = ((unsigned long long)u0 << 32) | (unsigned)mini0;
    unsigned u1 = __float_as_uint(minv1);
    u1 = (u1 & 0x80000000u) ? ~u1 : (u1 | 0x80000000u);
    unsigned long long k1 = ((unsigned long long)u1 << 32) | (unsigned)mini1;
    unsigned long long o0 = __shfl_xor(k0, 32, 64);
    if (o0 < k0) k0 = o0;
    unsigned long long o1 = __shfl_xor(k1, 32, 64);
    if (o1 < k1) k1 = o1;
    if (h == 0) {
        red[l31 * 4 + wid]        = k0;
        red[(32 + l31) * 4 + wid] = k1;
    }
    __syncthreads();
    if (tid < 64) {
        unsigned long long a = red[tid * 4], b = red[tid * 4 + 1];
        unsigned long long c = red[tid * 4 + 2], d = red[tid * 4 + 3];
        unsigned long long m = (b < a) ? b : a;
        if (c < m) m = c;
        if (d < m) m = d;
        atomicMin(&packed[n0 + tid], m);
    }
}

// ------- zq_loss v3: LDS-staged coalesced + direct row-atomic emao accum -----
__global__ __launch_bounds__(256) void zq_loss(const float* __restrict__ z,
                                               const float* __restrict__ emb,
                                               const unsigned long long* __restrict__ packed,
                                               float* __restrict__ zq_out,
                                               float* __restrict__ idx_out,
                                               int* __restrict__ cnt_i,
                                               float* __restrict__ loss_sum,
                                               float* __restrict__ emao_out) {
    __shared__ float e_lds[64][68];
    __shared__ float z_lds[64][68];

    const int tid = threadIdx.x;
    const int n0  = blockIdx.x * 64;
    const int t   = tid >> 2, q = tid & 3;
    const int n   = n0 + t;
    const int w   = tid >> 6, lane = tid & 63;
    const int b   = n0 >> 10;            // whole block shares b
    const int hw0 = n0 & 1023;
    const int zb  = b * CHW + hw0;

    const int idx = (int)(packed[n] & 0xFFFFFFFFull);
    if (q == 0) {
        idx_out[n] = (float)idx;
        atomicAdd(&cnt_i[idx], 1);
    }
    // gather emb row -> e_lds[t][q*16..]
    {
        const float* er = emb + idx * 64 + q * 16;
        float4 e0 = *(const float4*)er,       e1 = *(const float4*)(er + 4);
        float4 e2 = *(const float4*)(er + 8), e3 = *(const float4*)(er + 12);
        *(float4*)&e_lds[t][q * 16]      = e0;
        *(float4*)&e_lds[t][q * 16 + 4]  = e1;
        *(float4*)&e_lds[t][q * 16 + 8]  = e2;
        *(float4*)&e_lds[t][q * 16 + 12] = e3;
    }
    // stage z channel-major (coalesced) -> z_lds[token][c]
    {
        const int f4 = tid & 15, c0 = tid >> 4;
        #pragma unroll
        for (int r = 0; r < 4; ++r) {
            int c = c0 * 4 + r;
            float4 v = *(const float4*)(z + zb + c * HWSZ + f4 * 4);
            z_lds[f4 * 4 + 0][c] = v.x;
            z_lds[f4 * 4 + 1][c] = v.y;
            z_lds[f4 * 4 + 2][c] = v.z;
            z_lds[f4 * 4 + 3][c] = v.w;
        }
    }
    __syncthreads();

    // emao accumulation: per wave, 16 tokens, one coalesced 256B burst each
    #pragma unroll
    for (int u = 0; u < 16; ++u) {
        int tt = w * 16 + u;
        int ix = __shfl(idx, u * 4, 64);    // lane u*4 holds token tt's idx
        atomicAdd(&emao_out[ix * 64 + lane], 0.01f * z_lds[tt][lane]);
    }

    // zq_out write: channel-major, fully coalesced; same per-element arithmetic
    {
        const int f4 = tid & 15, c0 = tid >> 4;
        #pragma unroll
        for (int r = 0; r < 4; ++r) {
            int c = c0 * 4 + r;
            float4 o;
            { float zv = z_lds[f4*4+0][c]; o.x = zv + (e_lds[f4*4+0][c] - zv); }
            { float zv = z_lds[f4*4+1][c]; o.y = zv + (e_lds[f4*4+1][c] - zv); }
            { float zv = z_lds[f4*4+2][c]; o.z = zv + (e_lds[f4*4+2][c] - zv); }
            { float zv = z_lds[f4*4+3][c]; o.w = zv + (e_lds[f4*4+3][c] - zv); }
            *(float4*)(zq_out + zb + c * HWSZ + f4 * 4) = o;
        }
    }
    // loss: per-thread order identical to R4 (c = q*16+j ascending)
    float lsum = 0.f;
    #pragma unroll
    for (int j = 0; j < 16; ++j) {
        int c = q * 16 + j;
        float dd = e_lds[t][c] - z_lds[t][c];
        lsum += dd * dd;
    }
    #pragma unroll
    for (int m = 32; m >= 1; m >>= 1) lsum += __shfl_xor(lsum, m, 64);
    if ((tid & 63) == 0) atomicAdd(loss_sum, lsum);
}

// ------- norm_div: csn + embo + loss in one parallel pass --------------------
// denom via identity sum(cnt) == N_TOK: denom = 0.99*S_cs + 0.01*N_TOK + 8192e-5.
__global__ __launch_bounds__(256) void norm_div(const int* __restrict__ cnt_i,
                                                const float* __restrict__ csize,
                                                const float* __restrict__ sums,
                                                const float* __restrict__ emao_out,
                                                float* __restrict__ csn_out,
                                                float* __restrict__ loss_out,
                                                float* __restrict__ embo_out) {
    const int g = blockIdx.x * 256 + threadIdx.x;   // 0..524287
    const int c = g >> 6;
    const float denom = 0.99f * sums[0] + 0.01f * (float)N_TOK + (float)(K_CODES * 1e-5);
    const float cv  = 0.99f * csize[c] + 0.01f * (float)cnt_i[c];
    const float csn = (cv + 1e-5f) / denom;
    if ((g & 63) == 0) csn_out[c] = csn;
    embo_out[g] = emao_out[g] / csn;
    if (g == 0) *loss_out = 0.25f * sums[1] * (1.0f / (float)NELEM);
}

extern "C" void kernel_launch(void* const* d_in, const int* in_sizes, int n_in,
                              void* d_out, int out_size, void* d_ws, size_t ws_size,
                              hipStream_t stream) {
    (void)in_sizes; (void)n_in; (void)out_size; (void)ws_size;
    const float* z     = (const float*)d_in[0];
    const float* emb   = (const float*)d_in[1];
    const float* ema_w = (const float*)d_in[2];
    const float* csize = (const float*)d_in[3];

    float* out      = (float*)d_out;
    float* zq_out   = out;
    float* loss_out = out + 2097152;
    float* idx_out  = out + 2097153;
    float* csn_out  = out + 2129921;
    float* emao_out = out + 2138113;
    float* embo_out = out + 2662401;

    char* wsb = (char*)d_ws;
    unsigned short*     blob    = (unsigned short*)(wsb);              // 2,097,152 B
    float*              eng     = (float*)(wsb + 2097152);             // 32 KB
    unsigned long long* packed  = (unsigned long long*)(wsb + 2129920);// 256 KB
    int*                cnt_i   = (int*)(wsb + 2523136);               // 32 KB
    float*              sums    = (float*)(wsb + 2555904);             // 8 B

    prep_e<<<128, 256, 0, stream>>>(emb, ema_w, csize, blob, eng, packed, cnt_i,
                                    sums, emao_out);
    vq_argmin<<<1024, 256, 0, stream>>>(z, blob, eng, packed);
    zq_loss<<<N_TOK / 64, 256, 0, stream>>>(z, emb, packed, zq_out, idx_out,
                                            cnt_i, sums + 1, emao_out);
    norm_div<<<NELEM / 4 / 256, 256, 0, stream>>>(cnt_i, csize, sums, emao_out,
                                                  csn_out, loss_out, embo_out);
}